// Round 7
// baseline (116.026 us; speedup 1.0000x reference)
//
#include <hip/hip_runtime.h>
#include <math.h>

// ModulationIndex as i8 MFMA GEMM, v7: single fused kernel.
// amp_sums[p*18+k, a] = sum_t onehot[pk, t] * amp[a, t]  (192x32x2048 / block)
// One block per (b,c,s): grid 256, 512 thr, ~38KB LDS.
// amp quantized q = floor(amp*65536) u16 -> lo/hi i8 planes (bias -128);
// two mfma_i32_16x16x64_i8 per K=64 chunk; exact integer reconstruction:
// sum_q = 256*acc_h + acc_l + 32896*cnt (cnt from ones column in lo plane).
// Epilogue in-kernel: entropy per (p,a), atomicAdd(0.25*MI) into d_out
// (zeroed via hipMemsetAsync on stream).

#define FP_ 10
#define FA_ 30
#define K_  18
#define T_  2048
#define TC_ 256
#define NTILE 8
#define NT_ 512

#define OFF_BINS 128
#define BINROW   2064                      // bytes per bins row (2048+16)
#define BSW_     516                       // words per bins row
#define OFF_LO   (OFF_BINS + FP_ * BINROW) // 20768
#define PROW     272                       // bytes per plane row (256+16)
#define PLSZ     (32 * PROW)               // 8704
#define OFF_HI   (OFF_LO + PLSZ)           // 29472
#define LDS_TOTAL (OFF_HI + PLSZ)          // 38176
#define OFF_RED  128                       // 192*33*4 = 25344 -> ends 25472
#define OFF_CNT  25472                     // +1536 = 27008 (dead lo-plane tail)

typedef int i32x4 __attribute__((ext_vector_type(4)));

// 0x01 at bytes of w equal to replicated byte kb4 (zero-byte trick).
static __device__ __forceinline__ unsigned oh8(unsigned w, unsigned kb4) {
  const unsigned x = w ^ kb4;
  const unsigned t = (x & 0x7F7F7F7Fu) + 0x7F7F7F7Fu;
  return ((~(t | x)) & 0x80808080u) >> 7;
}

__global__ __launch_bounds__(NT_, 2)
void mi_main(const float* __restrict__ pha, const float* __restrict__ amp,
             float* __restrict__ out) {
  extern __shared__ unsigned char smem[];
  float*    c_lds = (float*)smem;
  unsigned* binsw = (unsigned*)(smem + OFF_BINS);
  float*    red   = (float*)(smem + OFF_RED);
  int*      cnt_t = (int*)(smem + OFF_CNT);

  const int tid  = threadIdx.x;
  const int lane = tid & 63;
  const int wv   = tid >> 6;
  const int quad = lane >> 4;
  const int lc   = lane & 15;
  const int mq   = wv & 3;    // m-quarter: rows mq*48..+47
  const int q2   = wv >> 2;   // k-half

  const int g  = blockIdx.x;  // bc*4 + s
  const int s  = g & 3;
  const int bc = g >> 2;
  const long pha_base = (long)bc * (FP_ * 4L * T_) + (long)s * T_;
  const long amp_base = (long)bc * (FA_ * 4L * T_) + (long)s * T_;

  // cutoffs: bit-exact np.linspace(-pi, pi, 19) (f64 math, f32 cast)
  if (tid < 19) {
    const double PI_D = 3.14159265358979323846264338327950288;
    const double step = (2.0 * PI_D) / 18.0;
    c_lds[tid] = (tid == 18) ? (float)PI_D : (float)(-PI_D + (double)tid * step);
  }
  // static plane rows: 30 = ones in lo (counts, unbiased), zeros elsewhere
  if (tid < 17) {
    *(uint4*)(smem + OFF_LO + 30 * PROW + tid * 16) =
        make_uint4(0x01010101u, 0x01010101u, 0x01010101u, 0x01010101u);
    *(uint4*)(smem + OFF_LO + 31 * PROW + tid * 16) = make_uint4(0u, 0u, 0u, 0u);
    *(uint4*)(smem + OFF_HI + 30 * PROW + tid * 16) = make_uint4(0u, 0u, 0u, 0u);
    *(uint4*)(smem + OFF_HI + 31 * PROW + tid * 16) = make_uint4(0u, 0u, 0u, 0u);
  }

  // issue tile-0 amp loads first (latency hides under bins phase)
  const bool stager = tid < 480;
  const int a_row = tid >> 4;
  const int seg   = tid & 15;            // 16-t unit within tile
  const float* gsrc = amp + amp_base + (long)a_row * (4L * T_) + seg * 16;
  float4 vreg[4];
  if (stager) {
    #pragma unroll
    for (int j = 0; j < 4; ++j) vreg[j] = *(const float4*)(gsrc + j * 4);
  }

  // --- bins: 10 rows x 512 words (u8 bins, 4 t each); thread owns word tid.
  const float PI_F    = 3.14159274101257324f;
  const float INVSTEP = 2.8647890f;
  #pragma unroll 2
  for (int p = 0; p < FP_; ++p) {
    const float4 v = *(const float4*)(pha + pha_base + (long)p * (4L * T_) + tid * 4);
    const float xs[4] = {v.x, v.y, v.z, v.w};
    unsigned pk = 0;
    #pragma unroll
    for (int j = 0; j < 4; ++j) {
      const float x = xs[j];
      int gi = (int)((x + PI_F) * INVSTEP);
      gi = min(17, max(0, gi));
      if (x <= c_lds[gi]) gi -= 1;        // searchsorted-left: c_b < x <= c_{b+1}
      else if (x > c_lds[gi + 1]) gi += 1;
      gi = min(17, max(0, gi));
      pk |= ((unsigned)gi) << (8 * j);
    }
    binsw[p * BSW_ + tid] = pk;
  }

  // per-wave A-row tables (A operand: m = lane&15)
  int p_mt[3]; unsigned kb4_mt[3];
  #pragma unroll
  for (int mt = 0; mt < 3; ++mt) {
    const int row = mq * 48 + mt * 16 + lc;
    int p = row / 18; p = min(p, 9);
    const unsigned kb = (unsigned)(row - p * 18);   // >=18 on pad rows
    p_mt[mt] = p;
    kb4_mt[mt] = kb * 0x01010101u;
  }

  i32x4 accl[3][2], acch[3][2];
  #pragma unroll
  for (int mt = 0; mt < 3; ++mt) {
    accl[mt][0] = (i32x4){0,0,0,0}; accl[mt][1] = (i32x4){0,0,0,0};
    acch[mt][0] = (i32x4){0,0,0,0}; acch[mt][1] = (i32x4){0,0,0,0};
  }
  __syncthreads();   // bins + cutoffs + const rows visible

  #pragma unroll 1
  for (int tile = 0; tile < NTILE; ++tile) {
    if (stager) {   // quantize + byte-split + write 16 t into both planes
      unsigned lo[4], hi[4];
      #pragma unroll
      for (int j = 0; j < 4; ++j) {
        const float xv[4] = {vreg[j].x, vreg[j].y, vreg[j].z, vreg[j].w};
        unsigned q[4];
        #pragma unroll
        for (int e = 0; e < 4; ++e)
          q[e] = min((unsigned)(xv[e] * 65536.0f), 65535u);
        const unsigned w01 = q[0] | (q[1] << 16);
        const unsigned w23 = q[2] | (q[3] << 16);
        lo[j] = __builtin_amdgcn_perm(w23, w01, 0x06040200u) ^ 0x80808080u;
        hi[j] = __builtin_amdgcn_perm(w23, w01, 0x07050301u) ^ 0x80808080u;
      }
      *(uint4*)(smem + OFF_LO + a_row * PROW + seg * 16) = make_uint4(lo[0], lo[1], lo[2], lo[3]);
      *(uint4*)(smem + OFF_HI + a_row * PROW + seg * 16) = make_uint4(hi[0], hi[1], hi[2], hi[3]);
    }
    __syncthreads();
    if (stager && tile < NTILE - 1) {   // prefetch next tile during compute
      #pragma unroll
      for (int j = 0; j < 4; ++j)
        vreg[j] = *(const float4*)(gsrc + (tile + 1) * TC_ + j * 4);
    }

    #pragma unroll
    for (int ci = 0; ci < 2; ++ci) {
      const int cl = q2 * 2 + ci;                 // 64-t chunk 0..3 in tile
      const unsigned char* bl = smem + OFF_LO + cl * 64 + quad * 16;
      const unsigned char* bh = smem + OFF_HI + cl * 64 + quad * 16;
      const i32x4 Bl0 = *(const i32x4*)(bl + lc * PROW);
      const i32x4 Bl1 = *(const i32x4*)(bl + (16 + lc) * PROW);
      const i32x4 Bh0 = *(const i32x4*)(bh + lc * PROW);
      const i32x4 Bh1 = *(const i32x4*)(bh + (16 + lc) * PROW);
      const int chg = tile * 4 + cl;              // global 64-t chunk 0..31
      #pragma unroll
      for (int mt = 0; mt < 3; ++mt) {
        const uint4 wb = *(const uint4*)(smem + OFF_BINS + p_mt[mt] * BINROW
                                         + chg * 64 + quad * 16);
        const unsigned kb4 = kb4_mt[mt];
        const i32x4 A = (i32x4){(int)oh8(wb.x, kb4), (int)oh8(wb.y, kb4),
                                (int)oh8(wb.z, kb4), (int)oh8(wb.w, kb4)};
        accl[mt][0] = __builtin_amdgcn_mfma_i32_16x16x64_i8(A, Bl0, accl[mt][0], 0, 0, 0);
        acch[mt][0] = __builtin_amdgcn_mfma_i32_16x16x64_i8(A, Bh0, acch[mt][0], 0, 0, 0);
        accl[mt][1] = __builtin_amdgcn_mfma_i32_16x16x64_i8(A, Bl1, accl[mt][1], 0, 0, 0);
        acch[mt][1] = __builtin_amdgcn_mfma_i32_16x16x64_i8(A, Bh1, acch[mt][1], 0, 0, 0);
      }
    }
    __syncthreads();   // reads done before next tile's staging overwrite
  }

  // --- per-half counts table (col 30 = n=1, lc=14); C layout: row=quad*4+r
  if (lc == 14) {
    #pragma unroll
    for (int mt = 0; mt < 3; ++mt)
      #pragma unroll
      for (int r = 0; r < 4; ++r)
        cnt_t[q2 * 192 + mq * 48 + mt * 16 + quad * 4 + r] = accl[mt][1][r];
  }
  __syncthreads();

  // exact reconstruction to f32 per-half sums
  float vals[3][2][4];
  #pragma unroll
  for (int mt = 0; mt < 3; ++mt)
    #pragma unroll
    for (int n = 0; n < 2; ++n)
      #pragma unroll
      for (int r = 0; r < 4; ++r) {
        const int row = mq * 48 + mt * 16 + quad * 4 + r;
        const int cnt = cnt_t[q2 * 192 + row];
        const int raw = (acch[mt][n][r] << 8) + accl[mt][n][r] + 32896 * cnt;
        float v = (float)raw * 1.52587890625e-5f;   // / 65536
        if (n == 1 && lc == 14) v = (float)accl[mt][n][r];   // counts column raw
        vals[mt][n][r] = v;
      }
  __syncthreads();

  // k-half combine in red: q2==1 stores, q2==0 adds and stores final.
  if (q2 == 1) {
    float* S = &red[mq * 48 * 33];
    #pragma unroll
    for (int mt = 0; mt < 3; ++mt)
      #pragma unroll
      for (int n = 0; n < 2; ++n)
        #pragma unroll
        for (int r = 0; r < 4; ++r)
          S[(mt * 16 + quad * 4 + r) * 33 + n * 16 + lc] = vals[mt][n][r];
  }
  __syncthreads();
  if (q2 == 0) {
    float* S = &red[mq * 48 * 33];
    #pragma unroll
    for (int mt = 0; mt < 3; ++mt)
      #pragma unroll
      for (int n = 0; n < 2; ++n)
        #pragma unroll
        for (int r = 0; r < 4; ++r) {
          const int idx = (mt * 16 + quad * 4 + r) * 33 + n * 16 + lc;
          S[idx] = vals[mt][n][r] + S[idx];
        }
  }
  __syncthreads();

  // --- epilogue: entropy per (p,a); 300 threads; atomicAdd into out.
  if (tid < FP_ * FA_) {
    const int p = tid / FA_;
    const int a = tid - p * FA_;
    float m[K_];
    float tot = 0.0f;
    #pragma unroll
    for (int k = 0; k < K_; ++k) {
      const float cnt = red[(p * K_ + k) * 33 + 30];
      const float sv  = red[(p * K_ + k) * 33 + a];
      const float mk  = sv / (cnt + 1e-9f);
      m[k] = mk;
      tot += mk;
    }
    const float denom = tot + 1e-9f;
    float ent = 0.0f;
    #pragma unroll
    for (int k = 0; k < K_; ++k) {
      const float pr = m[k] / denom;
      ent += pr * logf(pr + 1e-9f);
    }
    const float L  = logf(18.0f);
    const float mi = (L + ent) / L;
    atomicAdd(&out[(bc * FP_ + p) * FA_ + a], 0.25f * mi);
  }
}

extern "C" void kernel_launch(void* const* d_in, const int* in_sizes, int n_in,
                              void* d_out, int out_size, void* d_ws, size_t ws_size,
                              hipStream_t stream) {
  const float* pha = (const float*)d_in[0];
  const float* amp = (const float*)d_in[1];
  float* out = (float*)d_out;

  hipMemsetAsync(d_out, 0, (size_t)out_size * sizeof(float), stream);
  hipLaunchKernelGGL(mi_main, dim3(256), dim3(NT_), LDS_TOTAL, stream, pha, amp, out);
}